// Round 8
// baseline (167.620 us; speedup 1.0000x reference)
//
#include <hip/hip_runtime.h>
#include <hip/hip_bf16.h>

#define B_  64
#define T_  1000
#define F_  140
#define D_  256
#define EPS_ 1e-5f

// k3 time-chunking: tau=2 => v-influence decays 2^-step; W=24 warmup steps from
// v=0 reproduce the true LIF state to <6e-8 before any written step.
#define CL_ 50
#define NC_ 20
#define W_  24

// k1u: GEMM+conv chunking. 64 h-rows per block -> 58 conv outputs.
#define CV_  58
#define NCV_ 18     // 58*18 = 1044 >= 1000
#define HST3_ 268   // hbuf row stride (shorts)
#define AST_ 168    // A row stride (shorts), K padded 140->160

// k2s: LIF1 scan chunking: 24 warm + 40 written = 64 staged rows.
#define SCL_ 40
#define SNC_ 25     // 40*25 = 1000

typedef __attribute__((ext_vector_type(8))) short bf16x8;
typedef __attribute__((ext_vector_type(4))) short bf16x4;
typedef __attribute__((ext_vector_type(4))) float f32x4;
typedef unsigned long long u64;

static __device__ inline short f2bf(float f) {
  __hip_bfloat16 h = __float2bfloat16(f);
  return *reinterpret_cast<short*>(&h);
}
static __device__ inline float bf2f(short s) {
  unsigned int u = ((unsigned int)(unsigned short)s) << 16;
  return __uint_as_float(u);
}

// ---------------- K0: lwT transpose + pw_w -> MFMA B-fragment layout (global)
__global__ __launch_bounds__(256) void k0_prep(const float* __restrict__ lw,
                                               float* __restrict__ lwT,
                                               const float* __restrict__ pw,
                                               short* __restrict__ wfrag) {
  int i = blockIdx.x * 256 + threadIdx.x;
  if (i < 65536) {
    int e = i >> 8, d = i & 255;
    lwT[(size_t)d * D_ + e] = lw[(size_t)e * D_ + d];
  } else if (i < 65536 + 40960) {
    int j = i - 65536;
    int q = j & 7;
    int lane = (j >> 3) & 63;
    int rest = j >> 9;              // ntile*5 + kk
    int kk = rest % 5, ntile = rest / 5;
    int n = ntile * 16 + (lane & 15);
    int k = kk * 32 + (lane >> 4) * 8 + q;
    wfrag[j] = (k < F_) ? f2bf(pw[(size_t)n * F_ + k]) : (short)0;
  }
}

// ---------------- K1u: pointwise GEMM + depthwise conv (K=7) + BN1 -> u_half bf16
// grid = (b, chunk). No serial phase. h rows r<->t=tb+r, tb = 58c-3; conv outputs
// t = 58c..58c+57 -> u[t][b][d] = 0.5*(conv*sc1+sh1) in bf16.
__global__ __launch_bounds__(256) void k1u(const float* __restrict__ x,
                                           const short* __restrict__ wfrag,
                                           const float* __restrict__ bias,
                                           const float* __restrict__ dww,
                                           const float* __restrict__ g1,
                                           const float* __restrict__ b1,
                                           const float* __restrict__ m1,
                                           const float* __restrict__ v1,
                                           short* __restrict__ u) {
  __shared__ short smem[64 * HST3_];        // 34,304 B
  short* Abuf = smem;                        // 64 x AST_, consumed before overlay
  short* hbuf = smem;                        // 64 x HST3_
  const int b = blockIdx.x;
  const int c = blockIdx.y;
  const int tb = CV_ * c - 3;
  const int tid = threadIdx.x;
  const int lane = tid & 63, wv = tid >> 6;
  const int lr = lane & 15, quad = lane >> 4;

  // ---- A stage: 4 threads/row, float4 segments (36/36/36/32 floats), cvt bf16
  {
    const int arow = tid >> 2, aseg = tid & 3;
    const int ak0 = aseg * 36;
    const int anum4 = (aseg == 3) ? 8 : 9;
    const int ta = tb + arow;
    short* adst = Abuf + arow * AST_ + ak0;
    if (ta >= 0 && ta < T_) {
      const float* xrow = x + ((size_t)b * T_ + ta) * F_ + ak0;
#pragma unroll
      for (int q = 0; q < 9; q++) {
        if (q < anum4) {
          float4 av = *(const float4*)(xrow + q * 4);
          bf16x4 pk = {f2bf(av.x), f2bf(av.y), f2bf(av.z), f2bf(av.w)};
          *(bf16x4*)(adst + q * 4) = pk;
        }
      }
    } else {
      bf16x4 z = {0, 0, 0, 0};
#pragma unroll
      for (int q = 0; q < 9; q++)
        if (q < anum4) *(bf16x4*)(adst + q * 4) = z;
    }
    if (aseg == 3) {
      bf16x4 z = {0, 0, 0, 0};
#pragma unroll
      for (int q = 0; q < 5; q++) *(bf16x4*)(adst + 32 + q * 4) = z;
    }
  }
  __syncthreads();

  // ---- GEMM: M=64 rows, N=256 (wave owns 64 n), K=160. B frags from global (L2).
  f32x4 acc[4][4] = {};
  const short* wfb = wfrag + (size_t)(wv * 4 * 5) * 512 + lane * 8;
#pragma unroll
  for (int kk = 0; kk < 5; kk++) {
    bf16x8 bfr[4], af[4];
#pragma unroll
    for (int j = 0; j < 4; j++)
      bfr[j] = *(const bf16x8*)(wfb + (size_t)(j * 5 + kk) * 512);
#pragma unroll
    for (int i = 0; i < 4; i++)
      af[i] = *(const bf16x8*)(Abuf + (i * 16 + lr) * AST_ + kk * 32 + quad * 8);
#pragma unroll
    for (int i = 0; i < 4; i++)
#pragma unroll
      for (int j = 0; j < 4; j++)
        acc[i][j] = __builtin_amdgcn_mfma_f32_16x16x32_bf16(af[i], bfr[j], acc[i][j], 0, 0, 0);
  }
  __syncthreads();                           // A consumed; hbuf overlays

  // ---- epilogue: C + bias -> hbuf bf16; t outside [0,T) -> 0 (conv zero-pad)
#pragma unroll
  for (int j = 0; j < 4; j++) {
    const int n = wv * 64 + j * 16 + lr;
    const float badd = bias[n];
#pragma unroll
    for (int i = 0; i < 4; i++) {
#pragma unroll
      for (int r = 0; r < 4; r++) {
        const int row = i * 16 + quad * 4 + r;
        const int t = tb + row;
        short val = (t >= 0 && t < T_) ? f2bf(acc[i][j][r] + badd) : (short)0;
        hbuf[row * HST3_ + n] = val;
      }
    }
  }
  __syncthreads();

  // ---- conv + BN1, in-place per column (column d private to thread d).
  // output row r (=t-3-tb... r_out) stored into hbuf row r_out (free: already consumed).
  {
    const int d = tid;
    const float scv = g1[d] * rsqrtf(v1[d] + EPS_);
    float w2[7];
#pragma unroll
    for (int k = 0; k < 7; k++) w2[k] = dww[d * 7 + k] * (0.5f * scv);
    const float sh2 = 0.5f * (b1[d] - m1[d] * scv);

    float win0 = bf2f(hbuf[0 * HST3_ + d]);
    float win1 = bf2f(hbuf[1 * HST3_ + d]);
    float win2 = bf2f(hbuf[2 * HST3_ + d]);
    float win3 = bf2f(hbuf[3 * HST3_ + d]);
    float win4 = bf2f(hbuf[4 * HST3_ + d]);
    float win5 = bf2f(hbuf[5 * HST3_ + d]);
#pragma unroll
    for (int r = 0; r < CV_; r++) {
      float tap = bf2f(hbuf[(r + 6) * HST3_ + d]);
      float uh = win0 * w2[0] + win1 * w2[1] + win2 * w2[2] + win3 * w2[3] +
                 win4 * w2[4] + win5 * w2[5] + tap * w2[6] + sh2;
      hbuf[r * HST3_ + d] = f2bf(uh);
      win0 = win1; win1 = win2; win2 = win3; win3 = win4; win4 = win5; win5 = tap;
    }
  }
  __syncthreads();

  // ---- store u rows 0..57 (t = 58c + r) as coalesced 16B vectors
  {
    const int t0 = CV_ * c;
#pragma unroll
    for (int ii = 0; ii < 8; ii++) {
      const int i = tid + ii * 256;
      if (i < CV_ * 32) {
        const int r = i >> 5, v8 = i & 31;
        const int t = t0 + r;
        if (t < T_) {
          *(bf16x8*)(u + ((size_t)t * B_ + b) * D_ + v8 * 8) =
              *(const bf16x8*)(hbuf + r * HST3_ + v8 * 8);
        }
      }
    }
  }
}

// ---------------- K2s: LIF1 scan over u_half -> spike bitmasks
// grid = (b, chunk of 40). Stage 64 rows (24 warm + 40 write) to LDS; warmup on
// zero-padded rows is a no-op (v stays 0), so trips are compile-time uniform.
__global__ __launch_bounds__(256) void k2s(const short* __restrict__ u,
                                           u64* __restrict__ bits) {
  __shared__ short uls[64 * D_];            // 32,768 B
  const int b = blockIdx.x;
  const int t0 = blockIdx.y * SCL_;
  const int tid = threadIdx.x;

  {
#pragma unroll
    for (int ii = 0; ii < 8; ii++) {
      const int i = tid + ii * 256;          // 64*32 = 2048 vec8 slots
      const int r = i >> 5, v8 = i & 31;
      const int t = t0 - W_ + r;
      bf16x8 val = {0, 0, 0, 0, 0, 0, 0, 0};
      if (t >= 0 && t < T_)
        val = *(const bf16x8*)(u + ((size_t)t * B_ + b) * D_ + v8 * 8);
      *(bf16x8*)(uls + r * D_ + v8 * 8) = val;
    }
  }
  __syncthreads();

  const int d = tid;
  const int lane = tid & 63, wv = tid >> 6;
  float v = 0.f;
#pragma unroll
  for (int s0 = 0; s0 < W_; s0 += 8) {      // 24 warmup steps
    float tap[8];
#pragma unroll
    for (int g = 0; g < 8; g++) tap[g] = bf2f(uls[(s0 + g) * D_ + d]);
#pragma unroll
    for (int g = 0; g < 8; g++) {
      v = 0.5f * v + tap[g];
      v = (v >= 1.0f) ? 0.f : v;
    }
  }
  u64* bp = bits + ((size_t)b * T_ + t0) * 4 + wv;
  const bool lane0 = (lane == 0);
#pragma unroll
  for (int s0 = 0; s0 < SCL_; s0 += 8) {    // 40 written steps
    float tap[8];
#pragma unroll
    for (int g = 0; g < 8; g++) tap[g] = bf2f(uls[(W_ + s0 + g) * D_ + d]);
#pragma unroll
    for (int g = 0; g < 8; g++) {
      v = 0.5f * v + tap[g];
      bool sp = (v >= 1.0f);
      u64 mask = __ballot(sp);
      if (lane0) bp[(size_t)(s0 + g) * 4] = mask;
      v = sp ? 0.f : v;
    }
  }
}

// ---------------- K3: sparse linear (spikes @ lin_w^T) + BN2 + LIF2 + residual
__global__ __launch_bounds__(256) void k3_lin_lif(const u64* __restrict__ bits,
                                                  const float* __restrict__ lwT,
                                                  const float* __restrict__ g2,
                                                  const float* __restrict__ b2,
                                                  const float* __restrict__ m2,
                                                  const float* __restrict__ v2,
                                                  float* __restrict__ out) {
  __shared__ u64 sb[(CL_ + W_) * 4];
  const int b = blockIdx.x;
  const int t0 = blockIdx.y * CL_;
  const int tstart = (t0 >= W_) ? t0 - W_ : 0;
  const int nwarm = t0 - tstart;            // 0 (chunk 0) or 24
  const int nsteps = nwarm + CL_;
  const int e = threadIdx.x;
  const u64* gbp = bits + ((size_t)b * T_ + tstart) * 4;
  for (int i = e; i < nsteps * 4; i += 256) sb[i] = gbp[i];
  __syncthreads();

  const float sc = g2[e] * rsqrtf(v2[e] + EPS_);
  const float shf = b2[e] - m2[e] * sc;
  const int eq = e >> 6, eb = e & 63;
  float v = 0.f;

  if (nwarm) {
#pragma unroll
    for (int s0 = 0; s0 < 24; s0 += 4) {
      u64 a0[4], a1[4], a2[4], a3[4];
#pragma unroll
      for (int g = 0; g < 4; g++) {
        a0[g] = sb[(s0 + g) * 4 + 0]; a1[g] = sb[(s0 + g) * 4 + 1];
        a2[g] = sb[(s0 + g) * 4 + 2]; a3[g] = sb[(s0 + g) * 4 + 3];
      }
#pragma unroll
      for (int g = 0; g < 4; g++) {
        float u = shf;
        if (a0[g] | a1[g] | a2[g] | a3[g]) {
          float acc = 0.f;
          u64 mm;
          mm = a0[g]; while (mm) { int l = __builtin_ctzll(mm); mm &= mm - 1; acc += lwT[(size_t)(l) * D_ + e]; }
          mm = a1[g]; while (mm) { int l = __builtin_ctzll(mm); mm &= mm - 1; acc += lwT[(size_t)(64 + l) * D_ + e]; }
          mm = a2[g]; while (mm) { int l = __builtin_ctzll(mm); mm &= mm - 1; acc += lwT[(size_t)(128 + l) * D_ + e]; }
          mm = a3[g]; while (mm) { int l = __builtin_ctzll(mm); mm &= mm - 1; acc += lwT[(size_t)(192 + l) * D_ + e]; }
          u = acc * sc + shf;
        }
        v = 0.5f * (v + u);
        v = (v >= 1.0f) ? 0.f : v;
      }
    }
  }
  float* op = out + ((size_t)t0 * B_ + b) * D_ + e;
  const size_t ts = (size_t)B_ * D_;
#pragma unroll
  for (int s0 = 0; s0 < 50; s0 += 5) {
    u64 a0[5], a1[5], a2[5], a3[5];
#pragma unroll
    for (int g = 0; g < 5; g++) {
      const int s = nwarm + s0 + g;
      a0[g] = sb[s * 4 + 0]; a1[g] = sb[s * 4 + 1];
      a2[g] = sb[s * 4 + 2]; a3[g] = sb[s * 4 + 3];
    }
#pragma unroll
    for (int g = 0; g < 5; g++) {
      float u = shf;
      if (a0[g] | a1[g] | a2[g] | a3[g]) {
        float acc = 0.f;
        u64 mm;
        mm = a0[g]; while (mm) { int l = __builtin_ctzll(mm); mm &= mm - 1; acc += lwT[(size_t)(l) * D_ + e]; }
        mm = a1[g]; while (mm) { int l = __builtin_ctzll(mm); mm &= mm - 1; acc += lwT[(size_t)(64 + l) * D_ + e]; }
        mm = a2[g]; while (mm) { int l = __builtin_ctzll(mm); mm &= mm - 1; acc += lwT[(size_t)(128 + l) * D_ + e]; }
        mm = a3[g]; while (mm) { int l = __builtin_ctzll(mm); mm &= mm - 1; acc += lwT[(size_t)(192 + l) * D_ + e]; }
        u = acc * sc + shf;
      }
      v = 0.5f * (v + u);
      bool sp = (v >= 1.0f);
      u64 myw = (eq == 0) ? a0[g] : (eq == 1) ? a1[g] : (eq == 2) ? a2[g] : a3[g];
      float s1 = (float)((myw >> eb) & 1ull);
      op[(size_t)(s0 + g) * ts] = (sp ? 1.0f : 0.0f) + s1;
      v = sp ? 0.f : v;
    }
  }
}

extern "C" void kernel_launch(void* const* d_in, const int* in_sizes, int n_in,
                              void* d_out, int out_size, void* d_ws, size_t ws_size,
                              hipStream_t stream) {
  const float* x    = (const float*)d_in[0];
  const float* pw_w = (const float*)d_in[1];
  const float* pw_b = (const float*)d_in[2];
  const float* dw_w = (const float*)d_in[3];
  const float* g1   = (const float*)d_in[4];
  const float* b1   = (const float*)d_in[5];
  const float* m1   = (const float*)d_in[6];
  const float* v1   = (const float*)d_in[7];
  const float* lw   = (const float*)d_in[8];
  const float* g2   = (const float*)d_in[9];
  const float* b2   = (const float*)d_in[10];
  const float* m2   = (const float*)d_in[11];
  const float* v2   = (const float*)d_in[12];
  float* out = (float*)d_out;

  char* ws = (char*)d_ws;
  short* u = (short*)ws;                                   // 32,768,000 B
  u64* bits = (u64*)(ws + 32768000);                       //  2,048,000 B
  float* lwT = (float*)(ws + 32768000 + 2048000);          //    262,144 B
  short* wfrag = (short*)(ws + 32768000 + 2048000 + 262144); //  81,920 B

  k0_prep<<<(65536 + 40960 + 255) / 256, 256, 0, stream>>>(lw, lwT, pw_w, wfrag);
  dim3 g_k1(B_, NCV_);
  k1u<<<g_k1, 256, 0, stream>>>(x, wfrag, pw_b, dw_w, g1, b1, m1, v1, u);
  dim3 g_k2(B_, SNC_);
  k2s<<<g_k2, 256, 0, stream>>>(u, bits);
  dim3 g_k3(B_, NC_);
  k3_lin_lif<<<g_k3, 256, 0, stream>>>(bits, lwT, g2, b2, m2, v2, out);
}

// Round 9
// 156.248 us; speedup vs baseline: 1.0728x; 1.0728x over previous
//
#include <hip/hip_runtime.h>
#include <hip/hip_bf16.h>

#define B_  64
#define T_  1000
#define F_  140
#define D_  256
#define EPS_ 1e-5f

// time-chunking: tau=2 => v-influence decays 2^-step; W=16 warmup steps from
// v=0 reproduce the true LIF state to ~3e-5 abs — far below the spike margin.
#define W2_ 16

// k3 chunking
#define CL_ 50
#define NC_ 20

// k12 chunking: 64 rows = 3 halo | 16 warm | 42 writes | 3 halo. row r <-> t = 42c-19+r.
#define CWR_ 42
#define NCH_ 24     // 42*24 = 1008 >= 1000
#define HST_ 268    // hbuf row stride (shorts): conflict-free b16 reads/writes
#define AST_ 168    // A row stride (shorts), K padded 140->160

typedef __attribute__((ext_vector_type(8))) short bf16x8;
typedef __attribute__((ext_vector_type(4))) short bf16x4;
typedef __attribute__((ext_vector_type(4))) float f32x4;
typedef unsigned long long u64;

static __device__ inline short f2bf(float f) {
  __hip_bfloat16 h = __float2bfloat16(f);
  return *reinterpret_cast<short*>(&h);
}
static __device__ inline float bf2f(short s) {
  unsigned int u = ((unsigned int)(unsigned short)s) << 16;
  return __uint_as_float(u);
}

// ---------------- K0: lwT transpose + pw_w -> MFMA B-fragment layout (global)
__global__ __launch_bounds__(256) void k0_prep(const float* __restrict__ lw,
                                               float* __restrict__ lwT,
                                               const float* __restrict__ pw,
                                               short* __restrict__ wfrag) {
  int i = blockIdx.x * 256 + threadIdx.x;
  if (i < 65536) {
    int e = i >> 8, d = i & 255;
    lwT[(size_t)d * D_ + e] = lw[(size_t)e * D_ + d];
  } else if (i < 65536 + 40960) {
    int j = i - 65536;
    int q = j & 7;
    int lane = (j >> 3) & 63;
    int rest = j >> 9;              // ntile*5 + kk
    int kk = rest % 5, ntile = rest / 5;
    int n = ntile * 16 + (lane & 15);
    int k = kk * 32 + (lane >> 4) * 8 + q;
    wfrag[j] = (k < F_) ? f2bf(pw[(size_t)n * F_ + k]) : (short)0;
  }
}

// ---------------- K12: fused pointwise-GEMM + depthwise conv + BN1 + LIF1 -> bits
// grid = (b, chunk). 256 threads / 4 waves. GEMM M=64 rows, N=256 (wave owns 64 n),
// K=160. A one-shot LDS stage; B frag-layout from global (L2), pipelined.
// bits layout: [b][dq][T] -> one coalesced 336B store per wave at scan end.
__global__ __launch_bounds__(256, 4) void k12_fused(const float* __restrict__ x,
                                                    const short* __restrict__ wfrag,
                                                    const float* __restrict__ bias,
                                                    const float* __restrict__ dww,
                                                    const float* __restrict__ g1,
                                                    const float* __restrict__ b1,
                                                    const float* __restrict__ m1,
                                                    const float* __restrict__ v1,
                                                    u64* __restrict__ bits) {
  __shared__ short smem[64 * HST_];         // 34,304 B
  short* Abuf = smem;                        // 64 x AST_, consumed before overlay
  short* hbuf = smem;                        // 64 x HST_
  const int b = blockIdx.x;
  const int c = blockIdx.y;
  const int tb = CWR_ * c - 19;              // row r <-> t = tb + r
  const int tid = threadIdx.x;
  const int lane = tid & 63, wv = tid >> 6;
  const int lr = lane & 15, quad = lane >> 4;

  // ---- A stage: 4 threads/row, float4 segments (36/36/36/32 floats), cvt bf16
  {
    const int arow = tid >> 2, aseg = tid & 3;
    const int ak0 = aseg * 36;
    const int anum4 = (aseg == 3) ? 8 : 9;
    const int ta = tb + arow;
    short* adst = Abuf + arow * AST_ + ak0;
    if (ta >= 0 && ta < T_) {
      const float* xrow = x + ((size_t)b * T_ + ta) * F_ + ak0;
#pragma unroll
      for (int q = 0; q < 9; q++) {
        if (q < anum4) {
          float4 av = *(const float4*)(xrow + q * 4);
          bf16x4 pk = {f2bf(av.x), f2bf(av.y), f2bf(av.z), f2bf(av.w)};
          *(bf16x4*)(adst + q * 4) = pk;
        }
      }
    } else {
      bf16x4 z = {0, 0, 0, 0};
#pragma unroll
      for (int q = 0; q < 9; q++)
        if (q < anum4) *(bf16x4*)(adst + q * 4) = z;
    }
    if (aseg == 3) {                         // zero-pad k in [140,160)
      bf16x4 z = {0, 0, 0, 0};
#pragma unroll
      for (int q = 0; q < 5; q++) *(bf16x4*)(adst + 32 + q * 4) = z;
    }
  }

  // first B fragments issued before the barrier (independent of LDS)
  const short* wfb = wfrag + (size_t)(wv * 4 * 5) * 512 + lane * 8;
  bf16x8 bfr[4];
#pragma unroll
  for (int j = 0; j < 4; j++)
    bfr[j] = *(const bf16x8*)(wfb + (size_t)(j * 5 + 0) * 512);
  __syncthreads();

  // ---- GEMM with pipelined B loads
  f32x4 acc[4][4] = {};
#pragma unroll
  for (int kk = 0; kk < 5; kk++) {
    bf16x8 bnext[4];
    if (kk < 4) {
#pragma unroll
      for (int j = 0; j < 4; j++)
        bnext[j] = *(const bf16x8*)(wfb + (size_t)(j * 5 + kk + 1) * 512);
    }
    bf16x8 af[4];
#pragma unroll
    for (int i = 0; i < 4; i++)
      af[i] = *(const bf16x8*)(Abuf + (i * 16 + lr) * AST_ + kk * 32 + quad * 8);
#pragma unroll
    for (int i = 0; i < 4; i++)
#pragma unroll
      for (int j = 0; j < 4; j++)
        acc[i][j] = __builtin_amdgcn_mfma_f32_16x16x32_bf16(af[i], bfr[j], acc[i][j], 0, 0, 0);
    if (kk < 4) {
#pragma unroll
      for (int j = 0; j < 4; j++) bfr[j] = bnext[j];
    }
  }
  __syncthreads();                           // A consumed; hbuf overlays

  // ---- epilogue: C + bias -> hbuf bf16; rows with t outside [0,T) -> 0
#pragma unroll
  for (int j = 0; j < 4; j++) {
    const int n = wv * 64 + j * 16 + lr;
    const float badd = bias[n];
#pragma unroll
    for (int i = 0; i < 4; i++) {
#pragma unroll
      for (int r = 0; r < 4; r++) {
        const int row = i * 16 + quad * 4 + r;
        const int t = tb + row;
        short val = (t >= 0 && t < T_) ? f2bf(acc[i][j][r] + badd) : (short)0;
        hbuf[row * HST_ + n] = val;
      }
    }
  }
  __syncthreads();

  // ---- depthwise conv (K=7) + BN1 + LIF1 scan: thread = d. Uniform trips:
  // warmup over zero-filled t<0 rows is a no-op, so no chunk-0 special case.
  {
    const int d = tid;
    const float scv = g1[d] * rsqrtf(v1[d] + EPS_);
    float w2[7];
#pragma unroll
    for (int k = 0; k < 7; k++) w2[k] = dww[d * 7 + k] * (0.5f * scv);
    const float sh2 = 0.5f * (b1[d] - m1[d] * scv);

    float win0 = bf2f(hbuf[0 * HST_ + d]);
    float win1 = bf2f(hbuf[1 * HST_ + d]);
    float win2 = bf2f(hbuf[2 * HST_ + d]);
    float win3 = bf2f(hbuf[3 * HST_ + d]);
    float win4 = bf2f(hbuf[4 * HST_ + d]);
    float win5 = bf2f(hbuf[5 * HST_ + d]);
    float v = 0.f;
    u64 mymask = 0;

    // 58 steps: s<16 warmup, s>=16 write step i=s-16 (ballot kept in lane i)
#pragma unroll
    for (int s0 = 0; s0 < 56; s0 += 8) {
      float tap[8];
#pragma unroll
      for (int g = 0; g < 8; g++) tap[g] = bf2f(hbuf[(s0 + g + 6) * HST_ + d]);
#pragma unroll
      for (int g = 0; g < 8; g++) {
        const int s = s0 + g;
        float u2 = win0 * w2[0] + win1 * w2[1] + win2 * w2[2] + win3 * w2[3] +
                   win4 * w2[4] + win5 * w2[5] + tap[g] * w2[6] + sh2;
        v = 0.5f * v + u2;
        bool sp = (v >= 1.0f);
        if (s >= W2_) {
          u64 mask = __ballot(sp);
          if (lane == (s - W2_)) mymask = mask;
        }
        v = sp ? 0.f : v;
        win0 = win1; win1 = win2; win2 = win3; win3 = win4; win4 = win5; win5 = tap[g];
      }
    }
    {                                        // steps 56, 57
      float tap[2];
#pragma unroll
      for (int g = 0; g < 2; g++) tap[g] = bf2f(hbuf[(56 + g + 6) * HST_ + d]);
#pragma unroll
      for (int g = 0; g < 2; g++) {
        const int s = 56 + g;
        float u2 = win0 * w2[0] + win1 * w2[1] + win2 * w2[2] + win3 * w2[3] +
                   win4 * w2[4] + win5 * w2[5] + tap[g] * w2[6] + sh2;
        v = 0.5f * v + u2;
        bool sp = (v >= 1.0f);
        u64 mask = __ballot(sp);
        if (lane == (s - W2_)) mymask = mask;
        v = sp ? 0.f : v;
        win0 = win1; win1 = win2; win2 = win3; win3 = win4; win4 = win5; win5 = tap[g];
      }
    }
    const int tw0 = CWR_ * c;
    if (lane < CWR_) {
      const int t = tw0 + lane;
      if (t < T_)
        bits[((size_t)b * 4 + wv) * T_ + t] = mymask;   // coalesced 336B per wave
    }
  }
}

// ---------------- K3: sparse linear (spikes @ lin_w^T) + BN2 + LIF2 + residual
// bits layout [b][dq][T]: stage 4 contiguous segments to LDS.
__global__ __launch_bounds__(256) void k3_lin_lif(const u64* __restrict__ bits,
                                                  const float* __restrict__ lwT,
                                                  const float* __restrict__ g2,
                                                  const float* __restrict__ b2,
                                                  const float* __restrict__ m2,
                                                  const float* __restrict__ v2,
                                                  float* __restrict__ out) {
  __shared__ u64 sb[4 * 80];
  const int b = blockIdx.x;
  const int t0 = blockIdx.y * CL_;
  const int tstart = (t0 >= W2_) ? t0 - W2_ : 0;
  const int nwarm = t0 - tstart;            // 0 (chunk 0) or 16
  const int nsteps = nwarm + CL_;           // 50 or 66
  const int e = threadIdx.x;
  {
    const int dq = e >> 6, sidx = e & 63;
    const u64* src = bits + ((size_t)b * 4 + dq) * T_ + tstart;
    if (sidx < nsteps) sb[dq * 80 + sidx] = src[sidx];
    const int s2 = sidx + 64;
    if (s2 < nsteps) sb[dq * 80 + s2] = src[s2];
  }
  __syncthreads();

  const float sc = g2[e] * rsqrtf(v2[e] + EPS_);
  const float shf = b2[e] - m2[e] * sc;
  const int eq = e >> 6, eb = e & 63;
  float v = 0.f;

  if (nwarm) {                              // fixed 16 warmup steps
#pragma unroll
    for (int s0 = 0; s0 < W2_; s0 += 4) {
      u64 a0[4], a1[4], a2[4], a3[4];
#pragma unroll
      for (int g = 0; g < 4; g++) {
        a0[g] = sb[0 * 80 + s0 + g]; a1[g] = sb[1 * 80 + s0 + g];
        a2[g] = sb[2 * 80 + s0 + g]; a3[g] = sb[3 * 80 + s0 + g];
      }
#pragma unroll
      for (int g = 0; g < 4; g++) {
        float u = shf;
        if (a0[g] | a1[g] | a2[g] | a3[g]) {   // wave-uniform
          float acc = 0.f;
          u64 mm;
          mm = a0[g]; while (mm) { int l = __builtin_ctzll(mm); mm &= mm - 1; acc += lwT[(size_t)(l) * D_ + e]; }
          mm = a1[g]; while (mm) { int l = __builtin_ctzll(mm); mm &= mm - 1; acc += lwT[(size_t)(64 + l) * D_ + e]; }
          mm = a2[g]; while (mm) { int l = __builtin_ctzll(mm); mm &= mm - 1; acc += lwT[(size_t)(128 + l) * D_ + e]; }
          mm = a3[g]; while (mm) { int l = __builtin_ctzll(mm); mm &= mm - 1; acc += lwT[(size_t)(192 + l) * D_ + e]; }
          u = acc * sc + shf;
        }
        v = 0.5f * (v + u);
        v = (v >= 1.0f) ? 0.f : v;
      }
    }
  }
  float* op = out + ((size_t)t0 * B_ + b) * D_ + e;
  const size_t ts = (size_t)B_ * D_;
#pragma unroll
  for (int s0 = 0; s0 < CL_; s0 += 5) {     // fixed 50 write steps
    u64 a0[5], a1[5], a2[5], a3[5];
#pragma unroll
    for (int g = 0; g < 5; g++) {
      const int s = nwarm + s0 + g;
      a0[g] = sb[0 * 80 + s]; a1[g] = sb[1 * 80 + s];
      a2[g] = sb[2 * 80 + s]; a3[g] = sb[3 * 80 + s];
    }
#pragma unroll
    for (int g = 0; g < 5; g++) {
      float u = shf;
      if (a0[g] | a1[g] | a2[g] | a3[g]) {
        float acc = 0.f;
        u64 mm;
        mm = a0[g]; while (mm) { int l = __builtin_ctzll(mm); mm &= mm - 1; acc += lwT[(size_t)(l) * D_ + e]; }
        mm = a1[g]; while (mm) { int l = __builtin_ctzll(mm); mm &= mm - 1; acc += lwT[(size_t)(64 + l) * D_ + e]; }
        mm = a2[g]; while (mm) { int l = __builtin_ctzll(mm); mm &= mm - 1; acc += lwT[(size_t)(128 + l) * D_ + e]; }
        mm = a3[g]; while (mm) { int l = __builtin_ctzll(mm); mm &= mm - 1; acc += lwT[(size_t)(192 + l) * D_ + e]; }
        u = acc * sc + shf;
      }
      v = 0.5f * (v + u);
      bool sp = (v >= 1.0f);
      u64 myw = (eq == 0) ? a0[g] : (eq == 1) ? a1[g] : (eq == 2) ? a2[g] : a3[g];
      float s1 = (float)((myw >> eb) & 1ull);
      op[(size_t)(s0 + g) * ts] = (sp ? 1.0f : 0.0f) + s1;
      v = sp ? 0.f : v;
    }
  }
}

extern "C" void kernel_launch(void* const* d_in, const int* in_sizes, int n_in,
                              void* d_out, int out_size, void* d_ws, size_t ws_size,
                              hipStream_t stream) {
  const float* x    = (const float*)d_in[0];
  const float* pw_w = (const float*)d_in[1];
  const float* pw_b = (const float*)d_in[2];
  const float* dw_w = (const float*)d_in[3];
  const float* g1   = (const float*)d_in[4];
  const float* b1   = (const float*)d_in[5];
  const float* m1   = (const float*)d_in[6];
  const float* v1   = (const float*)d_in[7];
  const float* lw   = (const float*)d_in[8];
  const float* g2   = (const float*)d_in[9];
  const float* b2   = (const float*)d_in[10];
  const float* m2   = (const float*)d_in[11];
  const float* v2   = (const float*)d_in[12];
  float* out = (float*)d_out;

  char* ws = (char*)d_ws;
  u64* bits = (u64*)ws;                                    // 2,048,000 B
  float* lwT = (float*)(ws + 2048000);                     //   262,144 B
  short* wfrag = (short*)(ws + 2048000 + 262144);          //    81,920 B

  k0_prep<<<(65536 + 40960 + 255) / 256, 256, 0, stream>>>(lw, lwT, pw_w, wfrag);
  dim3 g_k12(B_, NCH_);
  k12_fused<<<g_k12, 256, 0, stream>>>(x, wfrag, pw_b, dw_w, g1, b1, m1, v1, bits);
  dim3 g_k3(B_, NC_);
  k3_lin_lif<<<g_k3, 256, 0, stream>>>(bits, lwT, g2, b2, m2, v2, out);
}